// Round 7
// baseline (477.459 us; speedup 1.0000x reference)
//
#include <hip/hip_runtime.h>
#include <math.h>

#define H 8
#define NBLKA 256          // #chunks for hist/scatter passes
#define BTH 1024           // threads for hist/scatter (16 waves: latency hiding)
#define BSH 8              // 256 nodes per bucket
#define THL 512            // threads for sort/layer kernels (8 waves, 2 lanes/node)
#define POOLG 128          // max graphs spanned per block in pooling fast path

// ---- bf16 helpers (RNE pack, cheap unpack) ----
__device__ __forceinline__ unsigned pack2bf(float a, float b) {
    union { float f; unsigned u; } ua, ub;
    ua.f = a; ub.f = b;
    unsigned x = (ua.u + 0x7fffu + ((ua.u >> 16) & 1u)) >> 16;
    unsigned y = (ub.u + 0x7fffu + ((ub.u >> 16) & 1u)) >> 16;
    return x | (y << 16);
}
__device__ __forceinline__ float bf_lo(unsigned u) {
    union { unsigned u; float f; } c; c.u = u << 16; return c.f;
}
__device__ __forceinline__ float bf_hi(unsigned u) {
    union { unsigned u; float f; } c; c.u = u & 0xffff0000u; return c.f;
}

// ============== Phase A: per-block LDS histogram of dst buckets ==============
__global__ void histK(const int* __restrict__ ei, int E, int NB, int chunk,
                      int* __restrict__ hist, int* __restrict__ bucketTotal) {
    __shared__ int h[1024];
    int t = threadIdx.x, blk = blockIdx.x;
    for (int j = t; j < NB; j += BTH) h[j] = 0;
    __syncthreads();
    int s = blk * chunk, e = min(E, s + chunk);
    for (int i = s + t; i < e; i += BTH)
        atomicAdd(&h[__builtin_nontemporal_load(ei + E + i) >> BSH], 1);
    __syncthreads();
    for (int j = t; j < NB; j += BTH) {
        int v = h[j];
        hist[blk * NB + j] = v;
        if (v) atomicAdd(&bucketTotal[j], v);
    }
}

// ============== Phase B1: exclusive scan over bucket totals ==============
__global__ void scanBuckets(const int* __restrict__ bucketTotal, int NB,
                            int* __restrict__ bucketStart, int* __restrict__ nodeStart) {
    __shared__ int s[1024];
    int t = threadIdx.x;
    int my = (t < NB) ? bucketTotal[t] : 0;
    s[t] = my;
    __syncthreads();
    for (int off = 1; off < 1024; off <<= 1) {
        int v = (t >= off) ? s[t - off] : 0;
        __syncthreads();
        s[t] += v;
        __syncthreads();
    }
    if (t < NB) bucketStart[t] = s[t] - my;
    if (t == NB - 1) {
        bucketStart[NB] = s[t];
        nodeStart[(size_t)NB << BSH] = s[t];   // sentinel = E
    }
}

// ============== Phase B2: per-(block,bucket) start offsets ==============
__global__ void blockOffsets(const int* __restrict__ hist, const int* __restrict__ bucketStart,
                             int NB, int* __restrict__ blockStart) {
    __shared__ int s[NBLKA];
    int t = threadIdx.x, b = blockIdx.x;
    int my = hist[t * NB + b];
    s[t] = my;
    __syncthreads();
    for (int off = 1; off < NBLKA; off <<= 1) {
        int v = (t >= off) ? s[t - off] : 0;
        __syncthreads();
        s[t] += v;
        __syncthreads();
    }
    blockStart[t * NB + b] = bucketStart[b] + (s[t] - my);
}

// ============== Phase C: scatter edges into packed (src<<8|dstLow), bucket order ==============
// Cached stores (cursor-front lines write-combine in L2); NT stores cost 201MB (R5).
__global__ void scatterK(const int* __restrict__ ei, int E, int NB, int chunk,
                         const int* __restrict__ blockStart, unsigned* __restrict__ packed) {
    __shared__ int cur[1024];
    int t = threadIdx.x, blk = blockIdx.x;
    for (int j = t; j < NB; j += BTH) cur[j] = blockStart[blk * NB + j];
    __syncthreads();
    int s = blk * chunk, e = min(E, s + chunk);
    for (int i = s + t; i < e; i += BTH) {
        int src = __builtin_nontemporal_load(ei + i);
        int dst = __builtin_nontemporal_load(ei + E + i);
        int slot = atomicAdd(&cur[dst >> BSH], 1);
        packed[slot] = ((unsigned)src << 8) | (unsigned)(dst & 255);
    }
}

// ====== Phase D: in-bucket counting sort to exact-dst order -> srcSorted + nodeStart ======
__global__ void sortK(const unsigned* __restrict__ packed, const int* __restrict__ bucketStart,
                      unsigned* __restrict__ srcSorted, int* __restrict__ nodeStart) {
    __shared__ int cnt[256], sb[256], cur[256];
    int t = threadIdx.x, b = blockIdx.x;
    if (t < 256) cnt[t] = 0;
    __syncthreads();
    int s = bucketStart[b], e = bucketStart[b + 1];
    // pass 1: count exact dst (NT stream: don't evict caches)
    for (int i = s + t; i < e; i += THL)
        atomicAdd(&cnt[__builtin_nontemporal_load(packed + i) & 255u], 1);
    __syncthreads();
    // scan (Hillis-Steele over 256)
    if (t < 256) sb[t] = cnt[t];
    __syncthreads();
    for (int off = 1; off < 256; off <<= 1) {
        int add = (t < 256 && t >= off) ? sb[t - off] : 0;
        __syncthreads();
        if (t < 256) sb[t] += add;
        __syncthreads();
    }
    if (t < 256) {
        int excl = sb[t] - cnt[t];
        cur[t] = excl;
        nodeStart[(b << BSH) + t] = s + excl;
    }
    __syncthreads();
    // pass 2: scatter src into exact-dst order (writes contiguous in own segment)
    for (int i = s + t; i < e; i += THL) {
        unsigned p = __builtin_nontemporal_load(packed + i);
        int pos = atomicAdd(&cur[p & 255u], 1);
        srcSorted[s + pos] = p >> 8;
    }
}

// ====== Phase E: layer-1 = segmented gather-sum of x[src] + MLP1 + ELU -> h1 (bf16) ======
__global__ void layer1K(const unsigned* __restrict__ srcSorted, const int* __restrict__ nodeStart,
                        const float* __restrict__ x, int N,
                        const float* __restrict__ W1a, const float* __restrict__ b1a,
                        const float* __restrict__ W1b, const float* __restrict__ b1b,
                        unsigned* __restrict__ h1) {
    __shared__ float sW1a[H], sb1a[H], sW1b[H * H], sb1b[H];
    int t = threadIdx.x, b = blockIdx.x;
    if (t < H) { sW1a[t] = W1a[t]; sb1a[t] = b1a[t]; sb1b[t] = b1b[t]; }
    if (t >= 64 && t < 64 + H * H) sW1b[t - 64] = W1b[t - 64];
    __syncthreads();
    int gn = (b << BSH) + (t >> 1);
    int half = t & 1;
    int segS = nodeStart[gn], segE = nodeStart[gn + 1];
    float sum = 0.f;
    for (int k = segS + half; k < segE; k += 2)
        sum += x[__builtin_nontemporal_load(srcSorted + k)];   // NT: protect x residency
    sum += __shfl_xor(sum, 1, 64);
    if (half == 0 && gn < N) {
        float z = x[gn] + sum;
        float tv[H];
#pragma unroll
        for (int k = 0; k < H; k++) tv[k] = fmaxf(fmaf(z, sW1a[k], sb1a[k]), 0.f);
        float hv[H];
#pragma unroll
        for (int j = 0; j < H; j++) {
            float a = sb1b[j];
#pragma unroll
            for (int k = 0; k < H; k++) a += tv[k] * sW1b[k * H + j];
            hv[j] = a > 0.f ? a : (expf(a) - 1.f);   // elu
        }
        uint4 o;
        o.x = pack2bf(hv[0], hv[1]);
        o.y = pack2bf(hv[2], hv[3]);
        o.z = pack2bf(hv[4], hv[5]);
        o.w = pack2bf(hv[6], hv[7]);
        *(uint4*)(h1 + ((size_t)gn << 2)) = o;
    }
}

// ====== Phase F: layer-2 = segmented gather-sum of h1[src] + MLP2 + pooling ======
__global__ void layer2K(const unsigned* __restrict__ srcSorted, const int* __restrict__ nodeStart,
                        const unsigned* __restrict__ h1, int N,
                        const float* __restrict__ W2a, const float* __restrict__ b2a,
                        const float* __restrict__ W2b, const float* __restrict__ b2b,
                        const int* __restrict__ batch, float* __restrict__ sumsCnt) {
    __shared__ float pool[POOLG * 9];
    __shared__ float sW2a[H * H], sb2a[H], sW2b[H * H], sb2b[H];
    int t = threadIdx.x, b = blockIdx.x;
    if (t < H) { sb2a[t] = b2a[t]; sb2b[t] = b2b[t]; }
    if (t >= 64 && t < 64 + H * H) sW2a[t - 64] = W2a[t - 64];
    if (t >= 192 && t < 192 + H * H) sW2b[t - 192] = W2b[t - 192];
    __syncthreads();
    int gn = (b << BSH) + (t >> 1);
    int half = t & 1;
    int segS = nodeStart[gn], segE = nodeStart[gn + 1];
    const uint4* h1v = (const uint4*)h1;
    float a[H] = {0.f, 0.f, 0.f, 0.f, 0.f, 0.f, 0.f, 0.f};
    for (int k = segS + half; k < segE; k += 2) {
        // NT on the index stream (protects h1 L2 residency); cached on the gather.
        uint4 q = h1v[__builtin_nontemporal_load(srcSorted + k)];
        a[0] += bf_lo(q.x); a[1] += bf_hi(q.x);
        a[2] += bf_lo(q.y); a[3] += bf_hi(q.y);
        a[4] += bf_lo(q.z); a[5] += bf_hi(q.z);
        a[6] += bf_lo(q.w); a[7] += bf_hi(q.w);
    }
#pragma unroll
    for (int j = 0; j < H; j++) a[j] += __shfl_xor(a[j], 1, 64);
    bool valid = (half == 0) && (gn < N);
    float h2[H];
    int g = 0;
    if (valid) {
        uint4 q = h1v[gn];
        float z[H] = {bf_lo(q.x) + a[0], bf_hi(q.x) + a[1],
                      bf_lo(q.y) + a[2], bf_hi(q.y) + a[3],
                      bf_lo(q.z) + a[4], bf_hi(q.z) + a[5],
                      bf_lo(q.w) + a[6], bf_hi(q.w) + a[7]};
        float tv[H];
#pragma unroll
        for (int k = 0; k < H; k++) {
            float acc = sb2a[k];
#pragma unroll
            for (int j = 0; j < H; j++) acc += z[j] * sW2a[j * H + k];
            tv[k] = fmaxf(acc, 0.f);
        }
#pragma unroll
        for (int j = 0; j < H; j++) {
            float acc = sb2b[j];
#pragma unroll
            for (int k = 0; k < H; k++) acc += tv[k] * sW2b[k * H + j];
            h2[j] = acc;
        }
        g = batch[gn];
    }
    int gfirst = batch[min(b << BSH, N - 1)];
    int glast  = batch[min((b << BSH) + 255, N - 1)];
    int span = glast - gfirst + 1;
    if (span <= POOLG) {
        int span9 = span * 9;
        for (int j = t; j < span9; j += THL) pool[j] = 0.f;
        __syncthreads();
        if (valid) {
            float* p = &pool[(g - gfirst) * 9];
#pragma unroll
            for (int j = 0; j < H; j++) atomicAdd(p + j, h2[j]);
            atomicAdd(p + 8, 1.f);
        }
        __syncthreads();
        for (int j = t; j < span9; j += THL)
            atomicAdd(&sumsCnt[(size_t)gfirst * 9 + j], pool[j]);
    } else if (valid) {
        float* p = &sumsCnt[(size_t)g * 9];
#pragma unroll
        for (int j = 0; j < H; j++) atomicAdd(p + j, h2[j]);
        atomicAdd(p + 8, 1.f);
    }
}

__global__ void finalK(const float* __restrict__ sumsCnt, const float* __restrict__ Wfc,
                       const float* __restrict__ bfc, float* __restrict__ out, int G) {
    int g = blockIdx.x * blockDim.x + threadIdx.x;
    if (g >= G) return;
    const float* s = &sumsCnt[(size_t)g * 9];
    float c = fmaxf(s[8], 1.f);
    float dot = 0.f;
#pragma unroll
    for (int j = 0; j < H; j++) dot += s[j] * Wfc[j];
    float a = dot / c + bfc[0];
    out[g] = 1.f / (1.f + expf(-a));
}

// ============================ FALLBACK (R1 atomic path) ============================
__global__ void edge_agg1(const int* __restrict__ ei, const float* __restrict__ x,
                          float* __restrict__ agg1, int E) {
    int e = blockIdx.x * blockDim.x + threadIdx.x;
    if (e >= E) return;
    atomicAdd(&agg1[ei[E + e]], x[ei[e]]);
}
__global__ void node1F(const float* __restrict__ x, const float* __restrict__ agg1,
                       const float* __restrict__ W1a, const float* __restrict__ b1a,
                       const float* __restrict__ W1b, const float* __restrict__ b1b,
                       float* __restrict__ h1, int N) {
    int n = blockIdx.x * blockDim.x + threadIdx.x;
    if (n >= N) return;
    float z = x[n] + agg1[n];
    float tv[H];
#pragma unroll
    for (int k = 0; k < H; k++) tv[k] = fmaxf(z * W1a[k] + b1a[k], 0.f);
#pragma unroll
    for (int j = 0; j < H; j++) {
        float acc = b1b[j];
#pragma unroll
        for (int k = 0; k < H; k++) acc += tv[k] * W1b[k * H + j];
        h1[(size_t)n * H + j] = acc > 0.f ? acc : (expf(acc) - 1.f);
    }
}
__global__ void edge_agg2(const int* __restrict__ ei, const float* __restrict__ h1,
                          float* __restrict__ agg2, int E) {
    long long i = (long long)blockIdx.x * blockDim.x + threadIdx.x;
    if (i >= (long long)E * H) return;
    int e = (int)(i >> 3), k = (int)(i & 7);
    atomicAdd(&agg2[(size_t)ei[E + e] * H + k], h1[(size_t)ei[e] * H + k]);
}
__global__ void node2F(const float* __restrict__ h1, const float* __restrict__ agg2,
                       const float* __restrict__ W2a, const float* __restrict__ b2a,
                       const float* __restrict__ W2b, const float* __restrict__ b2b,
                       const int* __restrict__ batch,
                       float* __restrict__ sums, float* __restrict__ counts, int N) {
    int n = blockIdx.x * blockDim.x + threadIdx.x;
    if (n >= N) return;
    float z[H], tv[H];
#pragma unroll
    for (int j = 0; j < H; j++) z[j] = h1[(size_t)n * H + j] + agg2[(size_t)n * H + j];
#pragma unroll
    for (int k = 0; k < H; k++) {
        float a = b2a[k];
#pragma unroll
        for (int j = 0; j < H; j++) a += z[j] * W2a[j * H + k];
        tv[k] = fmaxf(a, 0.f);
    }
    int g = batch[n];
#pragma unroll
    for (int j = 0; j < H; j++) {
        float a = b2b[j];
#pragma unroll
        for (int k = 0; k < H; k++) a += tv[k] * W2b[k * H + j];
        atomicAdd(&sums[(size_t)g * H + j], a);
    }
    atomicAdd(&counts[g], 1.f);
}
__global__ void finalF(const float* __restrict__ sums, const float* __restrict__ counts,
                       const float* __restrict__ Wfc, const float* __restrict__ bfc,
                       float* __restrict__ out, int G) {
    int g = blockIdx.x * blockDim.x + threadIdx.x;
    if (g >= G) return;
    float c = fmaxf(counts[g], 1.f);
    float acc = bfc[0];
#pragma unroll
    for (int j = 0; j < H; j++) acc += (sums[(size_t)g * H + j] / c) * Wfc[j];
    out[g] = 1.f / (1.f + expf(-acc));
}

// ============================ LAUNCH ============================
extern "C" void kernel_launch(void* const* d_in, const int* in_sizes, int n_in,
                              void* d_out, int out_size, void* d_ws, size_t ws_size,
                              hipStream_t stream) {
    const float* x    = (const float*)d_in[0];
    const int*   ei   = (const int*)d_in[1];
    const int*   batch= (const int*)d_in[2];
    const float* W1a  = (const float*)d_in[3];
    const float* b1a  = (const float*)d_in[4];
    const float* W1b  = (const float*)d_in[5];
    const float* b1b  = (const float*)d_in[6];
    const float* W2a  = (const float*)d_in[7];
    const float* b2a  = (const float*)d_in[8];
    const float* W2b  = (const float*)d_in[9];
    const float* b2b  = (const float*)d_in[10];
    const float* Wfc  = (const float*)d_in[11];
    const float* bfc  = (const float*)d_in[12];

    const int N = in_sizes[0];
    const int E = in_sizes[1] / 2;
    const int G = out_size;
    const int NB = (N + 255) >> BSH;
    const int chunk = (E + NBLKA - 1) / NBLKA;
    const int B = 256;

    auto rnd4 = [](size_t v) { return (v + 3) & ~(size_t)3; };
    size_t o_bt   = 0;                                   // bucketTotal [1024] (zeroed)
    size_t o_sc   = 1024;                                // sumsCnt [9G]      (zeroed)
    size_t zelems = o_sc + (size_t)9 * G;                // ---- memset to here ----
    size_t o_hist = rnd4(zelems);                        // hist [NBLKA*NB]
    size_t o_bs   = rnd4(o_hist + (size_t)NBLKA * NB);   // bucketStart [NB+1]
    size_t o_bo   = rnd4(o_bs + NB + 1);                 // blockStart [NBLKA*NB]
    size_t o_pk   = rnd4(o_bo + (size_t)NBLKA * NB);     // packed [E]
    size_t o_ss   = rnd4(o_pk + (size_t)E);              // srcSorted [E]
    size_t o_ns   = rnd4(o_ss + (size_t)E);              // nodeStart [NB*256+1]
    size_t o_h1   = rnd4(o_ns + ((size_t)NB << BSH) + 1);// h1 bf16 [4*NB*256]
    size_t total  = o_h1 + ((size_t)NB << BSH) * 4;

    bool srcFits = (N <= (1 << 18));
    if (NB <= 1024 && srcFits && ws_size >= total * 4) {
        int*      wsi = (int*)d_ws;
        float*    wsf = (float*)d_ws;
        unsigned* wsu = (unsigned*)d_ws;
        int*      bucketTotal = wsi + o_bt;
        float*    sumsCnt     = wsf + o_sc;
        int*      hist        = wsi + o_hist;
        int*      bucketStart = wsi + o_bs;
        int*      blockStart  = wsi + o_bo;
        unsigned* packed      = wsu + o_pk;
        unsigned* srcSorted   = wsu + o_ss;
        int*      nodeStart   = wsi + o_ns;
        unsigned* h1          = wsu + o_h1;

        hipMemsetAsync(d_ws, 0, zelems * 4, stream);
        histK<<<NBLKA, BTH, 0, stream>>>(ei, E, NB, chunk, hist, bucketTotal);
        scanBuckets<<<1, 1024, 0, stream>>>(bucketTotal, NB, bucketStart, nodeStart);
        blockOffsets<<<NB, NBLKA, 0, stream>>>(hist, bucketStart, NB, blockStart);
        scatterK<<<NBLKA, BTH, 0, stream>>>(ei, E, NB, chunk, blockStart, packed);
        sortK<<<NB, THL, 0, stream>>>(packed, bucketStart, srcSorted, nodeStart);
        layer1K<<<NB, THL, 0, stream>>>(srcSorted, nodeStart, x, N, W1a, b1a, W1b, b1b, h1);
        layer2K<<<NB, THL, 0, stream>>>(srcSorted, nodeStart, h1, N, W2a, b2a, W2b, b2b,
                                        batch, sumsCnt);
        finalK<<<(G + B - 1) / B, B, 0, stream>>>(sumsCnt, Wfc, bfc, (float*)d_out, G);
    } else {
        float* ws     = (float*)d_ws;
        float* agg1   = ws;
        float* agg2   = agg1 + (size_t)N;
        float* sums   = agg2 + (size_t)8 * N;
        float* counts = sums + (size_t)8 * G;
        float* h1     = counts + (size_t)G;
        hipMemsetAsync(ws, 0, ((size_t)9 * N + (size_t)9 * G) * sizeof(float), stream);
        edge_agg1<<<(E + B - 1) / B, B, 0, stream>>>(ei, x, agg1, E);
        node1F<<<(N + B - 1) / B, B, 0, stream>>>(x, agg1, W1a, b1a, W1b, b1b, h1, N);
        long long tot = (long long)E * H;
        edge_agg2<<<(int)((tot + B - 1) / B), B, 0, stream>>>(ei, h1, agg2, E);
        node2F<<<(N + B - 1) / B, B, 0, stream>>>(h1, agg2, W2a, b2a, W2b, b2b, batch,
                                                  sums, counts, N);
        finalF<<<(G + B - 1) / B, B, 0, stream>>>(sums, counts, Wfc, bfc, (float*)d_out, G);
    }
}

// Round 8
// 381.302 us; speedup vs baseline: 1.2522x; 1.2522x over previous
//
#include <hip/hip_runtime.h>
#include <hip/hip_fp8.h>
#include <math.h>

#define H 8
#define NBLKA 256          // #chunks for hist/scatter passes
#define BTH 1024           // threads for hist/scatter
#define BSH 8              // 256 nodes per bucket
#define TS 1024            // threads for fused sort+layer1 and layer2 (4 lanes/node)
#define CAP 14336          // LDS capacity for in-bucket sorted srcs (56 KB)
#define POOLG 128          // max graphs spanned per block in pooling fast path

// ---- fp8 e4m3 helpers: HIP type for pack (RNE+sat), manual unpack ----
__device__ __forceinline__ unsigned f2fp8(float f) {
    __hip_fp8_e4m3 q(f);
    return (unsigned)q.__x;
}
__device__ __forceinline__ float fp8f(unsigned v) {
    unsigned e = (v >> 3) & 0xF, m = v & 7;
    float r;
    if (e == 0) r = (float)m * 0.001953125f;            // subnormal: m * 2^-9
    else { union { unsigned u; float f; } c; c.u = ((e + 120u) << 23) | (m << 20); r = c.f; }
    return (v & 0x80u) ? -r : r;
}

// ============== Phase A: per-block LDS histogram of dst buckets ==============
__global__ void histK(const int* __restrict__ ei, int E, int NB, int chunk,
                      int* __restrict__ hist, int* __restrict__ bucketTotal) {
    __shared__ int h[1024];
    int t = threadIdx.x, blk = blockIdx.x;
    for (int j = t; j < NB; j += BTH) h[j] = 0;
    __syncthreads();
    int s = blk * chunk, e = min(E, s + chunk);
    for (int i = s + t; i < e; i += BTH)
        atomicAdd(&h[__builtin_nontemporal_load(ei + E + i) >> BSH], 1);
    __syncthreads();
    for (int j = t; j < NB; j += BTH) {
        int v = h[j];
        hist[blk * NB + j] = v;
        if (v) atomicAdd(&bucketTotal[j], v);
    }
}

// ============== Phase B1: exclusive scan over bucket totals ==============
__global__ void scanBuckets(const int* __restrict__ bucketTotal, int NB,
                            int* __restrict__ bucketStart, int* __restrict__ nodeStart) {
    __shared__ int s[1024];
    int t = threadIdx.x;
    int my = (t < NB) ? bucketTotal[t] : 0;
    s[t] = my;
    __syncthreads();
    for (int off = 1; off < 1024; off <<= 1) {
        int v = (t >= off) ? s[t - off] : 0;
        __syncthreads();
        s[t] += v;
        __syncthreads();
    }
    if (t < NB) bucketStart[t] = s[t] - my;
    if (t == NB - 1) {
        bucketStart[NB] = s[t];
        nodeStart[(size_t)NB << BSH] = s[t];   // sentinel = E
    }
}

// ============== Phase B2: per-(block,bucket) start offsets ==============
__global__ void blockOffsets(const int* __restrict__ hist, const int* __restrict__ bucketStart,
                             int NB, int* __restrict__ blockStart) {
    __shared__ int s[NBLKA];
    int t = threadIdx.x, b = blockIdx.x;
    int my = hist[t * NB + b];
    s[t] = my;
    __syncthreads();
    for (int off = 1; off < NBLKA; off <<= 1) {
        int v = (t >= off) ? s[t - off] : 0;
        __syncthreads();
        s[t] += v;
        __syncthreads();
    }
    blockStart[t * NB + b] = bucketStart[b] + (s[t] - my);
}

// ============== Phase C: scatter edges into packed (src<<8|dstLow), bucket order ==============
// Cached stores (cursor-front lines write-combine in L2); NT stores cost 201MB (R5).
__global__ void scatterK(const int* __restrict__ ei, int E, int NB, int chunk,
                         const int* __restrict__ blockStart, unsigned* __restrict__ packed) {
    __shared__ int cur[1024];
    int t = threadIdx.x, blk = blockIdx.x;
    for (int j = t; j < NB; j += BTH) cur[j] = blockStart[blk * NB + j];
    __syncthreads();
    int s = blk * chunk, e = min(E, s + chunk);
    for (int i = s + t; i < e; i += BTH) {
        int src = __builtin_nontemporal_load(ei + i);
        int dst = __builtin_nontemporal_load(ei + E + i);
        int slot = atomicAdd(&cur[dst >> BSH], 1);
        packed[slot] = ((unsigned)src << 8) | (unsigned)(dst & 255);
    }
}

// ====== Phase D+E fused: in-bucket counting sort (LDS-resident) + layer-1 MLP -> h1 fp8 ======
__global__ void sortL1K(const unsigned* __restrict__ packed, const int* __restrict__ bucketStart,
                        const float* __restrict__ x, int N,
                        const float* __restrict__ W1a, const float* __restrict__ b1a,
                        const float* __restrict__ W1b, const float* __restrict__ b1b,
                        unsigned* __restrict__ srcSorted, int* __restrict__ nodeStart,
                        uint2* __restrict__ h1) {
    __shared__ unsigned ss[CAP];
    __shared__ int cnt[256], sb[256], cur[256];
    __shared__ float sW1a[H], sb1a[H], sW1b[H * H], sb1b[H];
    int t = threadIdx.x, b = blockIdx.x;
    if (t < 256) cnt[t] = 0;
    else if (t < 256 + H) { int j = t - 256; sW1a[j] = W1a[j]; sb1a[j] = b1a[j]; sb1b[j] = b1b[j]; }
    else if (t < 256 + H + H * H) { int j = t - 256 - H; sW1b[j] = W1b[j]; }
    __syncthreads();
    int s = bucketStart[b], e = bucketStart[b + 1];
    int n_e = e - s;
    // pass 1: count exact dst (NT stream)
    for (int i = s + t; i < e; i += TS)
        atomicAdd(&cnt[__builtin_nontemporal_load(packed + i) & 255u], 1);
    __syncthreads();
    if (t < 256) sb[t] = cnt[t];
    __syncthreads();
    for (int off = 1; off < 256; off <<= 1) {
        int add = (t < 256 && t >= off) ? sb[t - off] : 0;
        __syncthreads();
        if (t < 256) sb[t] += add;
        __syncthreads();
    }
    if (t < 256) {
        int excl = sb[t] - cnt[t];
        cur[t] = excl;
        nodeStart[(b << BSH) + t] = s + excl;
    }
    __syncthreads();
    bool inLds = (n_e <= CAP);
    // pass 2: scatter src into exact-dst order (LDS if it fits)
    for (int i = s + t; i < e; i += TS) {
        unsigned p = __builtin_nontemporal_load(packed + i);
        int pos = atomicAdd(&cur[p & 255u], 1);
        unsigned srcv = p >> 8;
        if (inLds) ss[pos] = srcv;
        else srcSorted[s + pos] = srcv;
    }
    __syncthreads();
    if (inLds)
        for (int i = t; i < n_e; i += TS) srcSorted[s + i] = ss[i];
    // layer-1: 4 lanes per node, gather x[src] from LDS-sorted list
    int node = t >> 2, q4 = t & 3;
    int gn = (b << BSH) + node;
    int lo = sb[node] - cnt[node], hi = sb[node];
    float sum = 0.f;
    if (inLds) {
        for (int k = lo + q4; k < hi; k += 4) sum += x[ss[k]];
    } else {
        for (int k = lo + q4; k < hi; k += 4) sum += x[srcSorted[s + k]];
    }
    sum += __shfl_xor(sum, 1, 64);
    sum += __shfl_xor(sum, 2, 64);
    if (q4 == 0 && gn < N) {
        float z = x[gn] + sum;
        float tv[H];
#pragma unroll
        for (int k = 0; k < H; k++) tv[k] = fmaxf(fmaf(z, sW1a[k], sb1a[k]), 0.f);
        float hv[H];
#pragma unroll
        for (int j = 0; j < H; j++) {
            float a = sb1b[j];
#pragma unroll
            for (int k = 0; k < H; k++) a += tv[k] * sW1b[k * H + j];
            hv[j] = a > 0.f ? a : (expf(a) - 1.f);   // elu
        }
        uint2 o;
        o.x = f2fp8(hv[0]) | (f2fp8(hv[1]) << 8) | (f2fp8(hv[2]) << 16) | (f2fp8(hv[3]) << 24);
        o.y = f2fp8(hv[4]) | (f2fp8(hv[5]) << 8) | (f2fp8(hv[6]) << 16) | (f2fp8(hv[7]) << 24);
        h1[gn] = o;
    }
}

// ====== Phase F: layer-2 = segmented fp8 gather-sum + MLP2 + pooling (4 lanes/node) ======
__global__ void layer2K(const unsigned* __restrict__ srcSorted, const int* __restrict__ nodeStart,
                        const uint2* __restrict__ h1, int N,
                        const float* __restrict__ W2a, const float* __restrict__ b2a,
                        const float* __restrict__ W2b, const float* __restrict__ b2b,
                        const int* __restrict__ batch, float* __restrict__ sumsCnt) {
    __shared__ float pool[POOLG * 9];
    __shared__ float sW2a[H * H], sb2a[H], sW2b[H * H], sb2b[H];
    int t = threadIdx.x, b = blockIdx.x;
    if (t < H) { sb2a[t] = b2a[t]; sb2b[t] = b2b[t]; }
    else if (t >= 64 && t < 64 + H * H) sW2a[t - 64] = W2a[t - 64];
    else if (t >= 192 && t < 192 + H * H) sW2b[t - 192] = W2b[t - 192];
    __syncthreads();
    int node = t >> 2, q4 = t & 3;
    int gn = (b << BSH) + node;
    int segS = nodeStart[gn], segE = nodeStart[gn + 1];
    float a[H] = {0.f, 0.f, 0.f, 0.f, 0.f, 0.f, 0.f, 0.f};
    for (int k = segS + q4; k < segE; k += 4) {
        uint2 v = h1[__builtin_nontemporal_load(srcSorted + k)];
        a[0] += fp8f(v.x & 255u);         a[1] += fp8f((v.x >> 8) & 255u);
        a[2] += fp8f((v.x >> 16) & 255u); a[3] += fp8f(v.x >> 24);
        a[4] += fp8f(v.y & 255u);         a[5] += fp8f((v.y >> 8) & 255u);
        a[6] += fp8f((v.y >> 16) & 255u); a[7] += fp8f(v.y >> 24);
    }
#pragma unroll
    for (int j = 0; j < H; j++) {
        a[j] += __shfl_xor(a[j], 1, 64);
        a[j] += __shfl_xor(a[j], 2, 64);
    }
    bool valid = (q4 == 0) && (gn < N);
    float h2[H];
    int g = 0;
    if (valid) {
        uint2 v = h1[gn];
        float z[H] = {fp8f(v.x & 255u) + a[0],         fp8f((v.x >> 8) & 255u) + a[1],
                      fp8f((v.x >> 16) & 255u) + a[2], fp8f(v.x >> 24) + a[3],
                      fp8f(v.y & 255u) + a[4],         fp8f((v.y >> 8) & 255u) + a[5],
                      fp8f((v.y >> 16) & 255u) + a[6], fp8f(v.y >> 24) + a[7]};
        float tv[H];
#pragma unroll
        for (int k = 0; k < H; k++) {
            float acc = sb2a[k];
#pragma unroll
            for (int j = 0; j < H; j++) acc += z[j] * sW2a[j * H + k];
            tv[k] = fmaxf(acc, 0.f);
        }
#pragma unroll
        for (int j = 0; j < H; j++) {
            float acc = sb2b[j];
#pragma unroll
            for (int k = 0; k < H; k++) acc += tv[k] * sW2b[k * H + j];
            h2[j] = acc;
        }
        g = batch[gn];
    }
    int gfirst = batch[min(b << BSH, N - 1)];
    int glast  = batch[min((b << BSH) + 255, N - 1)];
    int span = glast - gfirst + 1;
    if (span <= POOLG) {
        int span9 = span * 9;
        for (int j = t; j < span9; j += TS) pool[j] = 0.f;
        __syncthreads();
        if (valid) {
            float* p = &pool[(g - gfirst) * 9];
#pragma unroll
            for (int j = 0; j < H; j++) atomicAdd(p + j, h2[j]);
            atomicAdd(p + 8, 1.f);
        }
        __syncthreads();
        for (int j = t; j < span9; j += TS)
            atomicAdd(&sumsCnt[(size_t)gfirst * 9 + j], pool[j]);
    } else if (valid) {
        float* p = &sumsCnt[(size_t)g * 9];
#pragma unroll
        for (int j = 0; j < H; j++) atomicAdd(p + j, h2[j]);
        atomicAdd(p + 8, 1.f);
    }
}

__global__ void finalK(const float* __restrict__ sumsCnt, const float* __restrict__ Wfc,
                       const float* __restrict__ bfc, float* __restrict__ out, int G) {
    int g = blockIdx.x * blockDim.x + threadIdx.x;
    if (g >= G) return;
    const float* s = &sumsCnt[(size_t)g * 9];
    float c = fmaxf(s[8], 1.f);
    float dot = 0.f;
#pragma unroll
    for (int j = 0; j < H; j++) dot += s[j] * Wfc[j];
    float a = dot / c + bfc[0];
    out[g] = 1.f / (1.f + expf(-a));
}

// ============================ FALLBACK (R1 atomic path) ============================
__global__ void edge_agg1(const int* __restrict__ ei, const float* __restrict__ x,
                          float* __restrict__ agg1, int E) {
    int e = blockIdx.x * blockDim.x + threadIdx.x;
    if (e >= E) return;
    atomicAdd(&agg1[ei[E + e]], x[ei[e]]);
}
__global__ void node1F(const float* __restrict__ x, const float* __restrict__ agg1,
                       const float* __restrict__ W1a, const float* __restrict__ b1a,
                       const float* __restrict__ W1b, const float* __restrict__ b1b,
                       float* __restrict__ h1, int N) {
    int n = blockIdx.x * blockDim.x + threadIdx.x;
    if (n >= N) return;
    float z = x[n] + agg1[n];
    float tv[H];
#pragma unroll
    for (int k = 0; k < H; k++) tv[k] = fmaxf(z * W1a[k] + b1a[k], 0.f);
#pragma unroll
    for (int j = 0; j < H; j++) {
        float acc = b1b[j];
#pragma unroll
        for (int k = 0; k < H; k++) acc += tv[k] * W1b[k * H + j];
        h1[(size_t)n * H + j] = acc > 0.f ? acc : (expf(acc) - 1.f);
    }
}
__global__ void edge_agg2(const int* __restrict__ ei, const float* __restrict__ h1,
                          float* __restrict__ agg2, int E) {
    long long i = (long long)blockIdx.x * blockDim.x + threadIdx.x;
    if (i >= (long long)E * H) return;
    int e = (int)(i >> 3), k = (int)(i & 7);
    atomicAdd(&agg2[(size_t)ei[E + e] * H + k], h1[(size_t)ei[e] * H + k]);
}
__global__ void node2F(const float* __restrict__ h1, const float* __restrict__ agg2,
                       const float* __restrict__ W2a, const float* __restrict__ b2a,
                       const float* __restrict__ W2b, const float* __restrict__ b2b,
                       const int* __restrict__ batch,
                       float* __restrict__ sums, float* __restrict__ counts, int N) {
    int n = blockIdx.x * blockDim.x + threadIdx.x;
    if (n >= N) return;
    float z[H], tv[H];
#pragma unroll
    for (int j = 0; j < H; j++) z[j] = h1[(size_t)n * H + j] + agg2[(size_t)n * H + j];
#pragma unroll
    for (int k = 0; k < H; k++) {
        float a = b2a[k];
#pragma unroll
        for (int j = 0; j < H; j++) a += z[j] * W2a[j * H + k];
        tv[k] = fmaxf(a, 0.f);
    }
    int g = batch[n];
#pragma unroll
    for (int j = 0; j < H; j++) {
        float a = b2b[j];
#pragma unroll
        for (int k = 0; k < H; k++) a += tv[k] * W2b[k * H + j];
        atomicAdd(&sums[(size_t)g * H + j], a);
    }
    atomicAdd(&counts[g], 1.f);
}
__global__ void finalF(const float* __restrict__ sums, const float* __restrict__ counts,
                       const float* __restrict__ Wfc, const float* __restrict__ bfc,
                       float* __restrict__ out, int G) {
    int g = blockIdx.x * blockDim.x + threadIdx.x;
    if (g >= G) return;
    float c = fmaxf(counts[g], 1.f);
    float acc = bfc[0];
#pragma unroll
    for (int j = 0; j < H; j++) acc += (sums[(size_t)g * H + j] / c) * Wfc[j];
    out[g] = 1.f / (1.f + expf(-acc));
}

// ============================ LAUNCH ============================
extern "C" void kernel_launch(void* const* d_in, const int* in_sizes, int n_in,
                              void* d_out, int out_size, void* d_ws, size_t ws_size,
                              hipStream_t stream) {
    const float* x    = (const float*)d_in[0];
    const int*   ei   = (const int*)d_in[1];
    const int*   batch= (const int*)d_in[2];
    const float* W1a  = (const float*)d_in[3];
    const float* b1a  = (const float*)d_in[4];
    const float* W1b  = (const float*)d_in[5];
    const float* b1b  = (const float*)d_in[6];
    const float* W2a  = (const float*)d_in[7];
    const float* b2a  = (const float*)d_in[8];
    const float* W2b  = (const float*)d_in[9];
    const float* b2b  = (const float*)d_in[10];
    const float* Wfc  = (const float*)d_in[11];
    const float* bfc  = (const float*)d_in[12];

    const int N = in_sizes[0];
    const int E = in_sizes[1] / 2;
    const int G = out_size;
    const int NB = (N + 255) >> BSH;
    const int chunk = (E + NBLKA - 1) / NBLKA;
    const int B = 256;

    auto rnd4 = [](size_t v) { return (v + 3) & ~(size_t)3; };
    size_t o_bt   = 0;                                   // bucketTotal [1024] (zeroed)
    size_t o_sc   = 1024;                                // sumsCnt [9G]      (zeroed)
    size_t zelems = o_sc + (size_t)9 * G;                // ---- memset to here ----
    size_t o_hist = rnd4(zelems);                        // hist [NBLKA*NB]
    size_t o_bs   = rnd4(o_hist + (size_t)NBLKA * NB);   // bucketStart [NB+1]
    size_t o_bo   = rnd4(o_bs + NB + 1);                 // blockStart [NBLKA*NB]
    size_t o_pk   = rnd4(o_bo + (size_t)NBLKA * NB);     // packed [E]
    size_t o_ss   = rnd4(o_pk + (size_t)E);              // srcSorted [E]
    size_t o_ns   = rnd4(o_ss + (size_t)E);              // nodeStart [NB*256+1]
    size_t o_h1   = rnd4(o_ns + ((size_t)NB << BSH) + 1);// h1 fp8 [2*NB*256]
    size_t total  = o_h1 + ((size_t)NB << BSH) * 2;

    bool srcFits = (N <= (1 << 18));
    if (NB <= 1024 && srcFits && ws_size >= total * 4) {
        int*      wsi = (int*)d_ws;
        float*    wsf = (float*)d_ws;
        unsigned* wsu = (unsigned*)d_ws;
        int*      bucketTotal = wsi + o_bt;
        float*    sumsCnt     = wsf + o_sc;
        int*      hist        = wsi + o_hist;
        int*      bucketStart = wsi + o_bs;
        int*      blockStart  = wsi + o_bo;
        unsigned* packed      = wsu + o_pk;
        unsigned* srcSorted   = wsu + o_ss;
        int*      nodeStart   = wsi + o_ns;
        uint2*    h1          = (uint2*)(wsu + o_h1);

        hipMemsetAsync(d_ws, 0, zelems * 4, stream);
        histK<<<NBLKA, BTH, 0, stream>>>(ei, E, NB, chunk, hist, bucketTotal);
        scanBuckets<<<1, 1024, 0, stream>>>(bucketTotal, NB, bucketStart, nodeStart);
        blockOffsets<<<NB, NBLKA, 0, stream>>>(hist, bucketStart, NB, blockStart);
        scatterK<<<NBLKA, BTH, 0, stream>>>(ei, E, NB, chunk, blockStart, packed);
        sortL1K<<<NB, TS, 0, stream>>>(packed, bucketStart, x, N, W1a, b1a, W1b, b1b,
                                       srcSorted, nodeStart, h1);
        layer2K<<<NB, TS, 0, stream>>>(srcSorted, nodeStart, h1, N, W2a, b2a, W2b, b2b,
                                       batch, sumsCnt);
        finalK<<<(G + B - 1) / B, B, 0, stream>>>(sumsCnt, Wfc, bfc, (float*)d_out, G);
    } else {
        float* ws     = (float*)d_ws;
        float* agg1   = ws;
        float* agg2   = agg1 + (size_t)N;
        float* sums   = agg2 + (size_t)8 * N;
        float* counts = sums + (size_t)8 * G;
        float* h1     = counts + (size_t)G;
        hipMemsetAsync(ws, 0, ((size_t)9 * N + (size_t)9 * G) * sizeof(float), stream);
        edge_agg1<<<(E + B - 1) / B, B, 0, stream>>>(ei, x, agg1, E);
        node1F<<<(N + B - 1) / B, B, 0, stream>>>(x, agg1, W1a, b1a, W1b, b1b, h1, N);
        long long tot = (long long)E * H;
        edge_agg2<<<(int)((tot + B - 1) / B), B, 0, stream>>>(ei, h1, agg2, E);
        node2F<<<(N + B - 1) / B, B, 0, stream>>>(h1, agg2, W2a, b2a, W2b, b2b, batch,
                                                  sums, counts, N);
        finalF<<<(G + B - 1) / B, B, 0, stream>>>(sums, counts, Wfc, bfc, (float*)d_out, G);
    }
}

// Round 9
// 321.825 us; speedup vs baseline: 1.4836x; 1.1848x over previous
//
#include <hip/hip_runtime.h>
#include <hip/hip_fp8.h>
#include <math.h>

#define H 8
#define NBLKA 256          // #chunks for hist/scatter passes
#define BTH 1024           // threads for hist/scatter
#define BSH 8              // 256 nodes per bucket
#define TS 1024            // threads for fused sort+layer1 and layer2 (4 lanes/node)
#define CAP 14336          // LDS capacity for in-bucket sorted srcs (56 KB)
#define SCAP 25600         // LDS capacity for scatter chunk (100 KB)
#define POOLG 128          // max graphs spanned per block in pooling fast path

// ---- fp8 e4m3 helpers: HIP type for pack (RNE+sat), manual unpack ----
__device__ __forceinline__ unsigned f2fp8(float f) {
    __hip_fp8_e4m3 q(f);
    return (unsigned)q.__x;
}
__device__ __forceinline__ float fp8f(unsigned v) {
    unsigned e = (v >> 3) & 0xF, m = v & 7;
    float r;
    if (e == 0) r = (float)m * 0.001953125f;            // subnormal: m * 2^-9
    else { union { unsigned u; float f; } c; c.u = ((e + 120u) << 23) | (m << 20); r = c.f; }
    return (v & 0x80u) ? -r : r;
}

// ============== Phase A: per-block LDS histogram of dst buckets ==============
__global__ void histK(const int* __restrict__ ei, int E, int NB, int chunk,
                      int* __restrict__ hist, int* __restrict__ bucketTotal) {
    __shared__ int h[1024];
    int t = threadIdx.x, blk = blockIdx.x;
    for (int j = t; j < NB; j += BTH) h[j] = 0;
    __syncthreads();
    int s = blk * chunk, e = min(E, s + chunk);
    for (int i = s + t; i < e; i += BTH)
        atomicAdd(&h[__builtin_nontemporal_load(ei + E + i) >> BSH], 1);
    __syncthreads();
    for (int j = t; j < NB; j += BTH) {
        int v = h[j];
        hist[blk * NB + j] = v;
        if (v) atomicAdd(&bucketTotal[j], v);
    }
}

// ============== Phase B1: exclusive scan over bucket totals ==============
__global__ void scanBuckets(const int* __restrict__ bucketTotal, int NB,
                            int* __restrict__ bucketStart, int* __restrict__ nodeStart) {
    __shared__ int s[1024];
    int t = threadIdx.x;
    int my = (t < NB) ? bucketTotal[t] : 0;
    s[t] = my;
    __syncthreads();
    for (int off = 1; off < 1024; off <<= 1) {
        int v = (t >= off) ? s[t - off] : 0;
        __syncthreads();
        s[t] += v;
        __syncthreads();
    }
    if (t < NB) bucketStart[t] = s[t] - my;
    if (t == NB - 1) {
        bucketStart[NB] = s[t];
        nodeStart[(size_t)NB << BSH] = s[t];   // sentinel = E
    }
}

// ============== Phase B2: per-(block,bucket) start offsets ==============
__global__ void blockOffsets(const int* __restrict__ hist, const int* __restrict__ bucketStart,
                             int NB, int* __restrict__ blockStart) {
    __shared__ int s[NBLKA];
    int t = threadIdx.x, b = blockIdx.x;
    int my = hist[t * NB + b];
    s[t] = my;
    __syncthreads();
    for (int off = 1; off < NBLKA; off <<= 1) {
        int v = (t >= off) ? s[t - off] : 0;
        __syncthreads();
        s[t] += v;
        __syncthreads();
    }
    blockStart[t * NB + b] = bucketStart[b] + (s[t] - my);
}

// ====== Phase C: LDS-staged scatter — local bucket sort, then coalesced run copy-out ======
// Reuses histK's per-block histogram (no count atomics). Writes are wave-per-bucket,
// lane-per-element: consecutive lanes -> consecutive addresses -> full L2 lines.
// (R8: cursor-front scatter cost 150MB WRITE for 25.6MB payload.)
__global__ __launch_bounds__(BTH) void scatterK(const int* __restrict__ ei, int E, int NB,
                                                int chunk, const int* __restrict__ hist,
                                                const int* __restrict__ blockStart,
                                                unsigned* __restrict__ packed) {
    __shared__ unsigned ss[SCAP];
    __shared__ int sc[1024], lstart[1024], cur[1024];
    int t = threadIdx.x, blk = blockIdx.x;
    int c = (t < NB) ? hist[blk * NB + t] : 0;
    sc[t] = c;
    __syncthreads();
    for (int off = 1; off < 1024; off <<= 1) {
        int v = (t >= off) ? sc[t - off] : 0;
        __syncthreads();
        sc[t] += v;
        __syncthreads();
    }
    int excl = sc[t] - c;
    lstart[t] = excl;
    cur[t] = excl;
    __syncthreads();
    int s = blk * chunk, e = min(E, s + chunk);
    for (int i = s + t; i < e; i += BTH) {
        int src = __builtin_nontemporal_load(ei + i);
        int dst = __builtin_nontemporal_load(ei + E + i);
        int pos = atomicAdd(&cur[dst >> BSH], 1);
        ss[pos] = ((unsigned)src << 8) | (unsigned)(dst & 255);
    }
    __syncthreads();
    int wave = t >> 6, lane = t & 63;
    for (int j = wave; j < NB; j += (BTH >> 6)) {
        int ls = lstart[j];
        int n = sc[j] - ls;                 // this block's count for bucket j
        int gs = blockStart[blk * NB + j];
        for (int k = lane; k < n; k += 64)
            packed[gs + k] = ss[ls + k];
    }
}

// ====== Phase D+E fused: in-bucket counting sort (LDS-resident) + layer-1 MLP -> h1 fp8 ======
__global__ void sortL1K(const unsigned* __restrict__ packed, const int* __restrict__ bucketStart,
                        const float* __restrict__ x, int N,
                        const float* __restrict__ W1a, const float* __restrict__ b1a,
                        const float* __restrict__ W1b, const float* __restrict__ b1b,
                        unsigned* __restrict__ srcSorted, int* __restrict__ nodeStart,
                        uint2* __restrict__ h1) {
    __shared__ unsigned ss[CAP];
    __shared__ int cnt[256], sb[256], cur[256];
    __shared__ float sW1a[H], sb1a[H], sW1b[H * H], sb1b[H];
    int t = threadIdx.x, b = blockIdx.x;
    if (t < 256) cnt[t] = 0;
    else if (t < 256 + H) { int j = t - 256; sW1a[j] = W1a[j]; sb1a[j] = b1a[j]; sb1b[j] = b1b[j]; }
    else if (t < 256 + H + H * H) { int j = t - 256 - H; sW1b[j] = W1b[j]; }
    __syncthreads();
    int s = bucketStart[b], e = bucketStart[b + 1];
    int n_e = e - s;
    // pass 1: count exact dst (NT stream)
    for (int i = s + t; i < e; i += TS)
        atomicAdd(&cnt[__builtin_nontemporal_load(packed + i) & 255u], 1);
    __syncthreads();
    if (t < 256) sb[t] = cnt[t];
    __syncthreads();
    for (int off = 1; off < 256; off <<= 1) {
        int add = (t < 256 && t >= off) ? sb[t - off] : 0;
        __syncthreads();
        if (t < 256) sb[t] += add;
        __syncthreads();
    }
    if (t < 256) {
        int excl = sb[t] - cnt[t];
        cur[t] = excl;
        nodeStart[(b << BSH) + t] = s + excl;
    }
    __syncthreads();
    bool inLds = (n_e <= CAP);
    // pass 2: scatter src into exact-dst order (LDS if it fits)
    for (int i = s + t; i < e; i += TS) {
        unsigned p = __builtin_nontemporal_load(packed + i);
        int pos = atomicAdd(&cur[p & 255u], 1);
        unsigned srcv = p >> 8;
        if (inLds) ss[pos] = srcv;
        else srcSorted[s + pos] = srcv;
    }
    __syncthreads();
    if (inLds)
        for (int i = t; i < n_e; i += TS) srcSorted[s + i] = ss[i];
    // layer-1: 4 lanes per node, gather x[src] from LDS-sorted list
    int node = t >> 2, q4 = t & 3;
    int gn = (b << BSH) + node;
    int lo = sb[node] - cnt[node], hi = sb[node];
    float sum = 0.f;
    if (inLds) {
        for (int k = lo + q4; k < hi; k += 4) sum += x[ss[k]];
    } else {
        for (int k = lo + q4; k < hi; k += 4) sum += x[srcSorted[s + k]];
    }
    sum += __shfl_xor(sum, 1, 64);
    sum += __shfl_xor(sum, 2, 64);
    if (q4 == 0 && gn < N) {
        float z = x[gn] + sum;
        float tv[H];
#pragma unroll
        for (int k = 0; k < H; k++) tv[k] = fmaxf(fmaf(z, sW1a[k], sb1a[k]), 0.f);
        float hv[H];
#pragma unroll
        for (int j = 0; j < H; j++) {
            float a = sb1b[j];
#pragma unroll
            for (int k = 0; k < H; k++) a += tv[k] * sW1b[k * H + j];
            hv[j] = a > 0.f ? a : (expf(a) - 1.f);   // elu
        }
        uint2 o;
        o.x = f2fp8(hv[0]) | (f2fp8(hv[1]) << 8) | (f2fp8(hv[2]) << 16) | (f2fp8(hv[3]) << 24);
        o.y = f2fp8(hv[4]) | (f2fp8(hv[5]) << 8) | (f2fp8(hv[6]) << 16) | (f2fp8(hv[7]) << 24);
        h1[gn] = o;
    }
}

// ====== Phase F: layer-2 = segmented fp8 gather-sum + MLP2 + pooling (4 lanes/node) ======
__global__ void layer2K(const unsigned* __restrict__ srcSorted, const int* __restrict__ nodeStart,
                        const uint2* __restrict__ h1, int N,
                        const float* __restrict__ W2a, const float* __restrict__ b2a,
                        const float* __restrict__ W2b, const float* __restrict__ b2b,
                        const int* __restrict__ batch, float* __restrict__ sumsCnt) {
    __shared__ float pool[POOLG * 9];
    __shared__ float sW2a[H * H], sb2a[H], sW2b[H * H], sb2b[H];
    int t = threadIdx.x, b = blockIdx.x;
    if (t < H) { sb2a[t] = b2a[t]; sb2b[t] = b2b[t]; }
    else if (t >= 64 && t < 64 + H * H) sW2a[t - 64] = W2a[t - 64];
    else if (t >= 192 && t < 192 + H * H) sW2b[t - 192] = W2b[t - 192];
    __syncthreads();
    int node = t >> 2, q4 = t & 3;
    int gn = (b << BSH) + node;
    int segS = nodeStart[gn], segE = nodeStart[gn + 1];
    float a[H] = {0.f, 0.f, 0.f, 0.f, 0.f, 0.f, 0.f, 0.f};
    for (int k = segS + q4; k < segE; k += 4) {
        uint2 v = h1[__builtin_nontemporal_load(srcSorted + k)];
        a[0] += fp8f(v.x & 255u);         a[1] += fp8f((v.x >> 8) & 255u);
        a[2] += fp8f((v.x >> 16) & 255u); a[3] += fp8f(v.x >> 24);
        a[4] += fp8f(v.y & 255u);         a[5] += fp8f((v.y >> 8) & 255u);
        a[6] += fp8f((v.y >> 16) & 255u); a[7] += fp8f(v.y >> 24);
    }
#pragma unroll
    for (int j = 0; j < H; j++) {
        a[j] += __shfl_xor(a[j], 1, 64);
        a[j] += __shfl_xor(a[j], 2, 64);
    }
    bool valid = (q4 == 0) && (gn < N);
    float h2[H];
    int g = 0;
    if (valid) {
        uint2 v = h1[gn];
        float z[H] = {fp8f(v.x & 255u) + a[0],         fp8f((v.x >> 8) & 255u) + a[1],
                      fp8f((v.x >> 16) & 255u) + a[2], fp8f(v.x >> 24) + a[3],
                      fp8f(v.y & 255u) + a[4],         fp8f((v.y >> 8) & 255u) + a[5],
                      fp8f((v.y >> 16) & 255u) + a[6], fp8f(v.y >> 24) + a[7]};
        float tv[H];
#pragma unroll
        for (int k = 0; k < H; k++) {
            float acc = sb2a[k];
#pragma unroll
            for (int j = 0; j < H; j++) acc += z[j] * sW2a[j * H + k];
            tv[k] = fmaxf(acc, 0.f);
        }
#pragma unroll
        for (int j = 0; j < H; j++) {
            float acc = sb2b[j];
#pragma unroll
            for (int k = 0; k < H; k++) acc += tv[k] * sW2b[k * H + j];
            h2[j] = acc;
        }
        g = batch[gn];
    }
    int gfirst = batch[min(b << BSH, N - 1)];
    int glast  = batch[min((b << BSH) + 255, N - 1)];
    int span = glast - gfirst + 1;
    if (span <= POOLG) {
        int span9 = span * 9;
        for (int j = t; j < span9; j += TS) pool[j] = 0.f;
        __syncthreads();
        if (valid) {
            float* p = &pool[(g - gfirst) * 9];
#pragma unroll
            for (int j = 0; j < H; j++) atomicAdd(p + j, h2[j]);
            atomicAdd(p + 8, 1.f);
        }
        __syncthreads();
        for (int j = t; j < span9; j += TS)
            atomicAdd(&sumsCnt[(size_t)gfirst * 9 + j], pool[j]);
    } else if (valid) {
        float* p = &sumsCnt[(size_t)g * 9];
#pragma unroll
        for (int j = 0; j < H; j++) atomicAdd(p + j, h2[j]);
        atomicAdd(p + 8, 1.f);
    }
}

__global__ void finalK(const float* __restrict__ sumsCnt, const float* __restrict__ Wfc,
                       const float* __restrict__ bfc, float* __restrict__ out, int G) {
    int g = blockIdx.x * blockDim.x + threadIdx.x;
    if (g >= G) return;
    const float* s = &sumsCnt[(size_t)g * 9];
    float c = fmaxf(s[8], 1.f);
    float dot = 0.f;
#pragma unroll
    for (int j = 0; j < H; j++) dot += s[j] * Wfc[j];
    float a = dot / c + bfc[0];
    out[g] = 1.f / (1.f + expf(-a));
}

// ============================ FALLBACK (R1 atomic path) ============================
__global__ void edge_agg1(const int* __restrict__ ei, const float* __restrict__ x,
                          float* __restrict__ agg1, int E) {
    int e = blockIdx.x * blockDim.x + threadIdx.x;
    if (e >= E) return;
    atomicAdd(&agg1[ei[E + e]], x[ei[e]]);
}
__global__ void node1F(const float* __restrict__ x, const float* __restrict__ agg1,
                       const float* __restrict__ W1a, const float* __restrict__ b1a,
                       const float* __restrict__ W1b, const float* __restrict__ b1b,
                       float* __restrict__ h1, int N) {
    int n = blockIdx.x * blockDim.x + threadIdx.x;
    if (n >= N) return;
    float z = x[n] + agg1[n];
    float tv[H];
#pragma unroll
    for (int k = 0; k < H; k++) tv[k] = fmaxf(z * W1a[k] + b1a[k], 0.f);
#pragma unroll
    for (int j = 0; j < H; j++) {
        float acc = b1b[j];
#pragma unroll
        for (int k = 0; k < H; k++) acc += tv[k] * W1b[k * H + j];
        h1[(size_t)n * H + j] = acc > 0.f ? acc : (expf(acc) - 1.f);
    }
}
__global__ void edge_agg2(const int* __restrict__ ei, const float* __restrict__ h1,
                          float* __restrict__ agg2, int E) {
    long long i = (long long)blockIdx.x * blockDim.x + threadIdx.x;
    if (i >= (long long)E * H) return;
    int e = (int)(i >> 3), k = (int)(i & 7);
    atomicAdd(&agg2[(size_t)ei[E + e] * H + k], h1[(size_t)ei[e] * H + k]);
}
__global__ void node2F(const float* __restrict__ h1, const float* __restrict__ agg2,
                       const float* __restrict__ W2a, const float* __restrict__ b2a,
                       const float* __restrict__ W2b, const float* __restrict__ b2b,
                       const int* __restrict__ batch,
                       float* __restrict__ sums, float* __restrict__ counts, int N) {
    int n = blockIdx.x * blockDim.x + threadIdx.x;
    if (n >= N) return;
    float z[H], tv[H];
#pragma unroll
    for (int j = 0; j < H; j++) z[j] = h1[(size_t)n * H + j] + agg2[(size_t)n * H + j];
#pragma unroll
    for (int k = 0; k < H; k++) {
        float a = b2a[k];
#pragma unroll
        for (int j = 0; j < H; j++) a += z[j] * W2a[j * H + k];
        tv[k] = fmaxf(a, 0.f);
    }
    int g = batch[n];
#pragma unroll
    for (int j = 0; j < H; j++) {
        float a = b2b[j];
#pragma unroll
        for (int k = 0; k < H; k++) a += tv[k] * W2b[k * H + j];
        atomicAdd(&sums[(size_t)g * H + j], a);
    }
    atomicAdd(&counts[g], 1.f);
}
__global__ void finalF(const float* __restrict__ sums, const float* __restrict__ counts,
                       const float* __restrict__ Wfc, const float* __restrict__ bfc,
                       float* __restrict__ out, int G) {
    int g = blockIdx.x * blockDim.x + threadIdx.x;
    if (g >= G) return;
    float c = fmaxf(counts[g], 1.f);
    float acc = bfc[0];
#pragma unroll
    for (int j = 0; j < H; j++) acc += (sums[(size_t)g * H + j] / c) * Wfc[j];
    out[g] = 1.f / (1.f + expf(-acc));
}

// ============================ LAUNCH ============================
extern "C" void kernel_launch(void* const* d_in, const int* in_sizes, int n_in,
                              void* d_out, int out_size, void* d_ws, size_t ws_size,
                              hipStream_t stream) {
    const float* x    = (const float*)d_in[0];
    const int*   ei   = (const int*)d_in[1];
    const int*   batch= (const int*)d_in[2];
    const float* W1a  = (const float*)d_in[3];
    const float* b1a  = (const float*)d_in[4];
    const float* W1b  = (const float*)d_in[5];
    const float* b1b  = (const float*)d_in[6];
    const float* W2a  = (const float*)d_in[7];
    const float* b2a  = (const float*)d_in[8];
    const float* W2b  = (const float*)d_in[9];
    const float* b2b  = (const float*)d_in[10];
    const float* Wfc  = (const float*)d_in[11];
    const float* bfc  = (const float*)d_in[12];

    const int N = in_sizes[0];
    const int E = in_sizes[1] / 2;
    const int G = out_size;
    const int NB = (N + 255) >> BSH;
    const int chunk = (E + NBLKA - 1) / NBLKA;
    const int B = 256;

    auto rnd4 = [](size_t v) { return (v + 3) & ~(size_t)3; };
    size_t o_bt   = 0;                                   // bucketTotal [1024] (zeroed)
    size_t o_sc   = 1024;                                // sumsCnt [9G]      (zeroed)
    size_t zelems = o_sc + (size_t)9 * G;                // ---- memset to here ----
    size_t o_hist = rnd4(zelems);                        // hist [NBLKA*NB]
    size_t o_bs   = rnd4(o_hist + (size_t)NBLKA * NB);   // bucketStart [NB+1]
    size_t o_bo   = rnd4(o_bs + NB + 1);                 // blockStart [NBLKA*NB]
    size_t o_pk   = rnd4(o_bo + (size_t)NBLKA * NB);     // packed [E]
    size_t o_ss   = rnd4(o_pk + (size_t)E);              // srcSorted [E]
    size_t o_ns   = rnd4(o_ss + (size_t)E);              // nodeStart [NB*256+1]
    size_t o_h1   = rnd4(o_ns + ((size_t)NB << BSH) + 1);// h1 fp8 [2*NB*256]
    size_t total  = o_h1 + ((size_t)NB << BSH) * 2;

    bool srcFits = (N <= (1 << 18));
    bool chunkFits = (chunk <= SCAP);
    if (NB <= 1024 && srcFits && chunkFits && ws_size >= total * 4) {
        int*      wsi = (int*)d_ws;
        float*    wsf = (float*)d_ws;
        unsigned* wsu = (unsigned*)d_ws;
        int*      bucketTotal = wsi + o_bt;
        float*    sumsCnt     = wsf + o_sc;
        int*      hist        = wsi + o_hist;
        int*      bucketStart = wsi + o_bs;
        int*      blockStart  = wsi + o_bo;
        unsigned* packed      = wsu + o_pk;
        unsigned* srcSorted   = wsu + o_ss;
        int*      nodeStart   = wsi + o_ns;
        uint2*    h1          = (uint2*)(wsu + o_h1);

        hipMemsetAsync(d_ws, 0, zelems * 4, stream);
        histK<<<NBLKA, BTH, 0, stream>>>(ei, E, NB, chunk, hist, bucketTotal);
        scanBuckets<<<1, 1024, 0, stream>>>(bucketTotal, NB, bucketStart, nodeStart);
        blockOffsets<<<NB, NBLKA, 0, stream>>>(hist, bucketStart, NB, blockStart);
        scatterK<<<NBLKA, BTH, 0, stream>>>(ei, E, NB, chunk, hist, blockStart, packed);
        sortL1K<<<NB, TS, 0, stream>>>(packed, bucketStart, x, N, W1a, b1a, W1b, b1b,
                                       srcSorted, nodeStart, h1);
        layer2K<<<NB, TS, 0, stream>>>(srcSorted, nodeStart, h1, N, W2a, b2a, W2b, b2b,
                                       batch, sumsCnt);
        finalK<<<(G + B - 1) / B, B, 0, stream>>>(sumsCnt, Wfc, bfc, (float*)d_out, G);
    } else {
        float* ws     = (float*)d_ws;
        float* agg1   = ws;
        float* agg2   = agg1 + (size_t)N;
        float* sums   = agg2 + (size_t)8 * N;
        float* counts = sums + (size_t)8 * G;
        float* h1     = counts + (size_t)G;
        hipMemsetAsync(ws, 0, ((size_t)9 * N + (size_t)9 * G) * sizeof(float), stream);
        edge_agg1<<<(E + B - 1) / B, B, 0, stream>>>(ei, x, agg1, E);
        node1F<<<(N + B - 1) / B, B, 0, stream>>>(x, agg1, W1a, b1a, W1b, b1b, h1, N);
        long long tot = (long long)E * H;
        edge_agg2<<<(int)((tot + B - 1) / B), B, 0, stream>>>(ei, h1, agg2, E);
        node2F<<<(N + B - 1) / B, B, 0, stream>>>(h1, agg2, W2a, b2a, W2b, b2b, batch,
                                                  sums, counts, N);
        finalF<<<(G + B - 1) / B, B, 0, stream>>>(sums, counts, Wfc, bfc, (float*)d_out, G);
    }
}

// Round 10
// 312.726 us; speedup vs baseline: 1.5268x; 1.0291x over previous
//
#include <hip/hip_runtime.h>
#include <hip/hip_fp8.h>
#include <math.h>

#define H 8
#define NBLKA 256          // #chunks for hist/scatter passes
#define BTH 1024           // threads for hist/scatter
#define BSH 8              // 256 nodes per bucket
#define TS 1024            // threads for fused sort+layer1 (4 lanes/node)
#define CAP 14336          // LDS capacity for in-bucket sorted srcs (56 KB)
#define SCAP 25600         // LDS capacity for scatter chunk (100 KB)
#define POOLG 128          // max graphs spanned per block in pooling fast path
#define NPB2 128           // nodes per block in layer2 (8 lanes/node, 1024 thr)

// ---- fp8 e4m3 helpers via HIP type (HW cvt on gfx950) ----
__device__ __forceinline__ unsigned f2fp8(float f) {
    __hip_fp8_e4m3 q(f);
    return (unsigned)q.__x;
}
__device__ __forceinline__ float fp8f(unsigned v) {
    __hip_fp8_e4m3 q;
    q.__x = (__hip_fp8_storage_t)v;
    return (float)q;
}

// ============== Phase A: per-block LDS histogram of dst buckets ==============
__global__ void histK(const int* __restrict__ ei, int E, int NB, int chunk,
                      int* __restrict__ hist, int* __restrict__ bucketTotal) {
    __shared__ int h[1024];
    int t = threadIdx.x, blk = blockIdx.x;
    for (int j = t; j < NB; j += BTH) h[j] = 0;
    __syncthreads();
    int s = blk * chunk, e = min(E, s + chunk);
    for (int i = s + t; i < e; i += BTH)
        atomicAdd(&h[__builtin_nontemporal_load(ei + E + i) >> BSH], 1);
    __syncthreads();
    for (int j = t; j < NB; j += BTH) {
        int v = h[j];
        hist[blk * NB + j] = v;
        if (v) atomicAdd(&bucketTotal[j], v);
    }
}

// ============== Phase B1: exclusive scan over bucket totals ==============
__global__ void scanBuckets(const int* __restrict__ bucketTotal, int NB,
                            int* __restrict__ bucketStart, int* __restrict__ nodeStart) {
    __shared__ int s[1024];
    int t = threadIdx.x;
    int my = (t < NB) ? bucketTotal[t] : 0;
    s[t] = my;
    __syncthreads();
    for (int off = 1; off < 1024; off <<= 1) {
        int v = (t >= off) ? s[t - off] : 0;
        __syncthreads();
        s[t] += v;
        __syncthreads();
    }
    if (t < NB) bucketStart[t] = s[t] - my;
    if (t == NB - 1) {
        bucketStart[NB] = s[t];
        nodeStart[(size_t)NB << BSH] = s[t];   // sentinel = E
    }
}

// ============== Phase B2: per-(block,bucket) start offsets ==============
__global__ void blockOffsets(const int* __restrict__ hist, const int* __restrict__ bucketStart,
                             int NB, int* __restrict__ blockStart) {
    __shared__ int s[NBLKA];
    int t = threadIdx.x, b = blockIdx.x;
    int my = hist[t * NB + b];
    s[t] = my;
    __syncthreads();
    for (int off = 1; off < NBLKA; off <<= 1) {
        int v = (t >= off) ? s[t - off] : 0;
        __syncthreads();
        s[t] += v;
        __syncthreads();
    }
    blockStart[t * NB + b] = bucketStart[b] + (s[t] - my);
}

// ====== Phase C: LDS-staged scatter — local bucket sort, then coalesced run copy-out ======
__global__ __launch_bounds__(BTH) void scatterK(const int* __restrict__ ei, int E, int NB,
                                                int chunk, const int* __restrict__ hist,
                                                const int* __restrict__ blockStart,
                                                unsigned* __restrict__ packed) {
    __shared__ unsigned ss[SCAP];
    __shared__ int sc[1024], lstart[1024], cur[1024];
    int t = threadIdx.x, blk = blockIdx.x;
    int c = (t < NB) ? hist[blk * NB + t] : 0;
    sc[t] = c;
    __syncthreads();
    for (int off = 1; off < 1024; off <<= 1) {
        int v = (t >= off) ? sc[t - off] : 0;
        __syncthreads();
        sc[t] += v;
        __syncthreads();
    }
    int excl = sc[t] - c;
    lstart[t] = excl;
    cur[t] = excl;
    __syncthreads();
    int s = blk * chunk, e = min(E, s + chunk);
    for (int i = s + t; i < e; i += BTH) {
        int src = __builtin_nontemporal_load(ei + i);
        int dst = __builtin_nontemporal_load(ei + E + i);
        int pos = atomicAdd(&cur[dst >> BSH], 1);
        ss[pos] = ((unsigned)src << 8) | (unsigned)(dst & 255);
    }
    __syncthreads();
    int wave = t >> 6, lane = t & 63;
    for (int j = wave; j < NB; j += (BTH >> 6)) {
        int ls = lstart[j];
        int n = sc[j] - ls;
        int gs = blockStart[blk * NB + j];
        for (int k = lane; k < n; k += 64)
            packed[gs + k] = ss[ls + k];
    }
}

// ====== Phase D+E fused: in-bucket counting sort (LDS-resident) + layer-1 MLP -> h1 fp8 ======
__global__ void sortL1K(const unsigned* __restrict__ packed, const int* __restrict__ bucketStart,
                        const float* __restrict__ x, int N,
                        const float* __restrict__ W1a, const float* __restrict__ b1a,
                        const float* __restrict__ W1b, const float* __restrict__ b1b,
                        unsigned* __restrict__ srcSorted, int* __restrict__ nodeStart,
                        uint2* __restrict__ h1) {
    __shared__ unsigned ss[CAP];
    __shared__ int cnt[256], sb[256], cur[256];
    __shared__ float sW1a[H], sb1a[H], sW1b[H * H], sb1b[H];
    int t = threadIdx.x, b = blockIdx.x;
    if (t < 256) cnt[t] = 0;
    else if (t < 256 + H) { int j = t - 256; sW1a[j] = W1a[j]; sb1a[j] = b1a[j]; sb1b[j] = b1b[j]; }
    else if (t < 256 + H + H * H) { int j = t - 256 - H; sW1b[j] = W1b[j]; }
    __syncthreads();
    int s = bucketStart[b], e = bucketStart[b + 1];
    int n_e = e - s;
    for (int i = s + t; i < e; i += TS)
        atomicAdd(&cnt[__builtin_nontemporal_load(packed + i) & 255u], 1);
    __syncthreads();
    if (t < 256) sb[t] = cnt[t];
    __syncthreads();
    for (int off = 1; off < 256; off <<= 1) {
        int add = (t < 256 && t >= off) ? sb[t - off] : 0;
        __syncthreads();
        if (t < 256) sb[t] += add;
        __syncthreads();
    }
    if (t < 256) {
        int excl = sb[t] - cnt[t];
        cur[t] = excl;
        nodeStart[(b << BSH) + t] = s + excl;
    }
    __syncthreads();
    bool inLds = (n_e <= CAP);
    for (int i = s + t; i < e; i += TS) {
        unsigned p = __builtin_nontemporal_load(packed + i);
        int pos = atomicAdd(&cur[p & 255u], 1);
        unsigned srcv = p >> 8;
        if (inLds) ss[pos] = srcv;
        else srcSorted[s + pos] = srcv;
    }
    __syncthreads();
    if (inLds)
        for (int i = t; i < n_e; i += TS) srcSorted[s + i] = ss[i];
    int node = t >> 2, q4 = t & 3;
    int gn = (b << BSH) + node;
    int lo = sb[node] - cnt[node], hi = sb[node];
    float sum = 0.f;
    if (inLds) {
        for (int k = lo + q4; k < hi; k += 4) sum += x[ss[k]];
    } else {
        for (int k = lo + q4; k < hi; k += 4) sum += x[srcSorted[s + k]];
    }
    sum += __shfl_xor(sum, 1, 64);
    sum += __shfl_xor(sum, 2, 64);
    if (q4 == 0 && gn < N) {
        float z = x[gn] + sum;
        float tv[H];
#pragma unroll
        for (int k = 0; k < H; k++) tv[k] = fmaxf(fmaf(z, sW1a[k], sb1a[k]), 0.f);
        float hv[H];
#pragma unroll
        for (int j = 0; j < H; j++) {
            float a = sb1b[j];
#pragma unroll
            for (int k = 0; k < H; k++) a += tv[k] * sW1b[k * H + j];
            hv[j] = a > 0.f ? a : (expf(a) - 1.f);   // elu
        }
        uint2 o;
        o.x = f2fp8(hv[0]) | (f2fp8(hv[1]) << 8) | (f2fp8(hv[2]) << 16) | (f2fp8(hv[3]) << 24);
        o.y = f2fp8(hv[4]) | (f2fp8(hv[5]) << 8) | (f2fp8(hv[6]) << 16) | (f2fp8(hv[7]) << 24);
        h1[gn] = o;
    }
}

// ====== Phase F: layer-2 = segmented fp8 gather-sum + MLP2 + pooling (8 lanes/node) ======
// Grid over nodes (NPB2/block), HW fp8 cvt decode, NT index stream.
__global__ __launch_bounds__(1024) void layer2K(
        const unsigned* __restrict__ srcSorted, const int* __restrict__ nodeStart,
        const uint2* __restrict__ h1, int N,
        const float* __restrict__ W2a, const float* __restrict__ b2a,
        const float* __restrict__ W2b, const float* __restrict__ b2b,
        const int* __restrict__ batch, float* __restrict__ sumsCnt) {
    __shared__ float pool[POOLG * 9];
    __shared__ float sW2a[H * H], sb2a[H], sW2b[H * H], sb2b[H];
    int t = threadIdx.x, b = blockIdx.x;
    if (t < H) { sb2a[t] = b2a[t]; sb2b[t] = b2b[t]; }
    else if (t >= 64 && t < 64 + H * H) sW2a[t - 64] = W2a[t - 64];
    else if (t >= 192 && t < 192 + H * H) sW2b[t - 192] = W2b[t - 192];
    __syncthreads();
    int node = t >> 3, lane8 = t & 7;
    int gn = b * NPB2 + node;                 // gn+1 <= NB*256 guaranteed by grid sizing
    int segS = nodeStart[gn], segE = nodeStart[gn + 1];
    float a[H] = {0.f, 0.f, 0.f, 0.f, 0.f, 0.f, 0.f, 0.f};
    for (int k = segS + lane8; k < segE; k += 8) {
        uint2 v = h1[__builtin_nontemporal_load(srcSorted + k)];
        a[0] += fp8f(v.x & 255u);         a[1] += fp8f((v.x >> 8) & 255u);
        a[2] += fp8f((v.x >> 16) & 255u); a[3] += fp8f(v.x >> 24);
        a[4] += fp8f(v.y & 255u);         a[5] += fp8f((v.y >> 8) & 255u);
        a[6] += fp8f((v.y >> 16) & 255u); a[7] += fp8f(v.y >> 24);
    }
#pragma unroll
    for (int j = 0; j < H; j++) {
        a[j] += __shfl_xor(a[j], 1, 64);
        a[j] += __shfl_xor(a[j], 2, 64);
        a[j] += __shfl_xor(a[j], 4, 64);
    }
    bool valid = (lane8 == 0) && (gn < N);
    float h2[H];
    int g = 0;
    if (valid) {
        uint2 v = h1[gn];
        float z[H] = {fp8f(v.x & 255u) + a[0],         fp8f((v.x >> 8) & 255u) + a[1],
                      fp8f((v.x >> 16) & 255u) + a[2], fp8f(v.x >> 24) + a[3],
                      fp8f(v.y & 255u) + a[4],         fp8f((v.y >> 8) & 255u) + a[5],
                      fp8f((v.y >> 16) & 255u) + a[6], fp8f(v.y >> 24) + a[7]};
        float tv[H];
#pragma unroll
        for (int k = 0; k < H; k++) {
            float acc = sb2a[k];
#pragma unroll
            for (int j = 0; j < H; j++) acc += z[j] * sW2a[j * H + k];
            tv[k] = fmaxf(acc, 0.f);
        }
#pragma unroll
        for (int j = 0; j < H; j++) {
            float acc = sb2b[j];
#pragma unroll
            for (int k = 0; k < H; k++) acc += tv[k] * sW2b[k * H + j];
            h2[j] = acc;
        }
        g = batch[gn];
    }
    int gfirst = batch[min(b * NPB2, N - 1)];
    int glast  = batch[min(b * NPB2 + NPB2 - 1, N - 1)];
    int span = glast - gfirst + 1;
    if (span <= POOLG) {
        int span9 = span * 9;
        for (int j = t; j < span9; j += 1024) pool[j] = 0.f;
        __syncthreads();
        if (valid) {
            float* p = &pool[(g - gfirst) * 9];
#pragma unroll
            for (int j = 0; j < H; j++) atomicAdd(p + j, h2[j]);
            atomicAdd(p + 8, 1.f);
        }
        __syncthreads();
        for (int j = t; j < span9; j += 1024)
            atomicAdd(&sumsCnt[(size_t)gfirst * 9 + j], pool[j]);
    } else if (valid) {
        float* p = &sumsCnt[(size_t)g * 9];
#pragma unroll
        for (int j = 0; j < H; j++) atomicAdd(p + j, h2[j]);
        atomicAdd(p + 8, 1.f);
    }
}

__global__ void finalK(const float* __restrict__ sumsCnt, const float* __restrict__ Wfc,
                       const float* __restrict__ bfc, float* __restrict__ out, int G) {
    int g = blockIdx.x * blockDim.x + threadIdx.x;
    if (g >= G) return;
    const float* s = &sumsCnt[(size_t)g * 9];
    float c = fmaxf(s[8], 1.f);
    float dot = 0.f;
#pragma unroll
    for (int j = 0; j < H; j++) dot += s[j] * Wfc[j];
    float a = dot / c + bfc[0];
    out[g] = 1.f / (1.f + expf(-a));
}

// ============================ FALLBACK (R1 atomic path) ============================
__global__ void edge_agg1(const int* __restrict__ ei, const float* __restrict__ x,
                          float* __restrict__ agg1, int E) {
    int e = blockIdx.x * blockDim.x + threadIdx.x;
    if (e >= E) return;
    atomicAdd(&agg1[ei[E + e]], x[ei[e]]);
}
__global__ void node1F(const float* __restrict__ x, const float* __restrict__ agg1,
                       const float* __restrict__ W1a, const float* __restrict__ b1a,
                       const float* __restrict__ W1b, const float* __restrict__ b1b,
                       float* __restrict__ h1, int N) {
    int n = blockIdx.x * blockDim.x + threadIdx.x;
    if (n >= N) return;
    float z = x[n] + agg1[n];
    float tv[H];
#pragma unroll
    for (int k = 0; k < H; k++) tv[k] = fmaxf(z * W1a[k] + b1a[k], 0.f);
#pragma unroll
    for (int j = 0; j < H; j++) {
        float acc = b1b[j];
#pragma unroll
        for (int k = 0; k < H; k++) acc += tv[k] * W1b[k * H + j];
        h1[(size_t)n * H + j] = acc > 0.f ? acc : (expf(acc) - 1.f);
    }
}
__global__ void edge_agg2(const int* __restrict__ ei, const float* __restrict__ h1,
                          float* __restrict__ agg2, int E) {
    long long i = (long long)blockIdx.x * blockDim.x + threadIdx.x;
    if (i >= (long long)E * H) return;
    int e = (int)(i >> 3), k = (int)(i & 7);
    atomicAdd(&agg2[(size_t)ei[E + e] * H + k], h1[(size_t)ei[e] * H + k]);
}
__global__ void node2F(const float* __restrict__ h1, const float* __restrict__ agg2,
                       const float* __restrict__ W2a, const float* __restrict__ b2a,
                       const float* __restrict__ W2b, const float* __restrict__ b2b,
                       const int* __restrict__ batch,
                       float* __restrict__ sums, float* __restrict__ counts, int N) {
    int n = blockIdx.x * blockDim.x + threadIdx.x;
    if (n >= N) return;
    float z[H], tv[H];
#pragma unroll
    for (int j = 0; j < H; j++) z[j] = h1[(size_t)n * H + j] + agg2[(size_t)n * H + j];
#pragma unroll
    for (int k = 0; k < H; k++) {
        float a = b2a[k];
#pragma unroll
        for (int j = 0; j < H; j++) a += z[j] * W2a[j * H + k];
        tv[k] = fmaxf(a, 0.f);
    }
    int g = batch[n];
#pragma unroll
    for (int j = 0; j < H; j++) {
        float a = b2b[j];
#pragma unroll
        for (int k = 0; k < H; k++) a += tv[k] * W2b[k * H + j];
        atomicAdd(&sums[(size_t)g * H + j], a);
    }
    atomicAdd(&counts[g], 1.f);
}
__global__ void finalF(const float* __restrict__ sums, const float* __restrict__ counts,
                       const float* __restrict__ Wfc, const float* __restrict__ bfc,
                       float* __restrict__ out, int G) {
    int g = blockIdx.x * blockDim.x + threadIdx.x;
    if (g >= G) return;
    float c = fmaxf(counts[g], 1.f);
    float acc = bfc[0];
#pragma unroll
    for (int j = 0; j < H; j++) acc += (sums[(size_t)g * H + j] / c) * Wfc[j];
    out[g] = 1.f / (1.f + expf(-acc));
}

// ============================ LAUNCH ============================
extern "C" void kernel_launch(void* const* d_in, const int* in_sizes, int n_in,
                              void* d_out, int out_size, void* d_ws, size_t ws_size,
                              hipStream_t stream) {
    const float* x    = (const float*)d_in[0];
    const int*   ei   = (const int*)d_in[1];
    const int*   batch= (const int*)d_in[2];
    const float* W1a  = (const float*)d_in[3];
    const float* b1a  = (const float*)d_in[4];
    const float* W1b  = (const float*)d_in[5];
    const float* b1b  = (const float*)d_in[6];
    const float* W2a  = (const float*)d_in[7];
    const float* b2a  = (const float*)d_in[8];
    const float* W2b  = (const float*)d_in[9];
    const float* b2b  = (const float*)d_in[10];
    const float* Wfc  = (const float*)d_in[11];
    const float* bfc  = (const float*)d_in[12];

    const int N = in_sizes[0];
    const int E = in_sizes[1] / 2;
    const int G = out_size;
    const int NB = (N + 255) >> BSH;
    const int chunk = (E + NBLKA - 1) / NBLKA;
    const int B = 256;

    auto rnd4 = [](size_t v) { return (v + 3) & ~(size_t)3; };
    size_t o_bt   = 0;                                   // bucketTotal [1024] (zeroed)
    size_t o_sc   = 1024;                                // sumsCnt [9G]      (zeroed)
    size_t zelems = o_sc + (size_t)9 * G;                // ---- memset to here ----
    size_t o_hist = rnd4(zelems);                        // hist [NBLKA*NB]
    size_t o_bs   = rnd4(o_hist + (size_t)NBLKA * NB);   // bucketStart [NB+1]
    size_t o_bo   = rnd4(o_bs + NB + 1);                 // blockStart [NBLKA*NB]
    size_t o_pk   = rnd4(o_bo + (size_t)NBLKA * NB);     // packed [E]
    size_t o_ss   = rnd4(o_pk + (size_t)E);              // srcSorted [E]
    size_t o_ns   = rnd4(o_ss + (size_t)E);              // nodeStart [NB*256+1]
    size_t o_h1   = rnd4(o_ns + ((size_t)NB << BSH) + 1);// h1 fp8 [2*NB*256]
    size_t total  = o_h1 + ((size_t)NB << BSH) * 2;

    bool srcFits = (N <= (1 << 18));
    bool chunkFits = (chunk <= SCAP);
    if (NB <= 1024 && srcFits && chunkFits && ws_size >= total * 4) {
        int*      wsi = (int*)d_ws;
        float*    wsf = (float*)d_ws;
        unsigned* wsu = (unsigned*)d_ws;
        int*      bucketTotal = wsi + o_bt;
        float*    sumsCnt     = wsf + o_sc;
        int*      hist        = wsi + o_hist;
        int*      bucketStart = wsi + o_bs;
        int*      blockStart  = wsi + o_bo;
        unsigned* packed      = wsu + o_pk;
        unsigned* srcSorted   = wsu + o_ss;
        int*      nodeStart   = wsi + o_ns;
        uint2*    h1          = (uint2*)(wsu + o_h1);

        hipMemsetAsync(d_ws, 0, zelems * 4, stream);
        histK<<<NBLKA, BTH, 0, stream>>>(ei, E, NB, chunk, hist, bucketTotal);
        scanBuckets<<<1, 1024, 0, stream>>>(bucketTotal, NB, bucketStart, nodeStart);
        blockOffsets<<<NB, NBLKA, 0, stream>>>(hist, bucketStart, NB, blockStart);
        scatterK<<<NBLKA, BTH, 0, stream>>>(ei, E, NB, chunk, hist, blockStart, packed);
        sortL1K<<<NB, TS, 0, stream>>>(packed, bucketStart, x, N, W1a, b1a, W1b, b1b,
                                       srcSorted, nodeStart, h1);
        layer2K<<<(N + NPB2 - 1) / NPB2, 1024, 0, stream>>>(srcSorted, nodeStart, h1, N,
                                                            W2a, b2a, W2b, b2b, batch, sumsCnt);
        finalK<<<(G + B - 1) / B, B, 0, stream>>>(sumsCnt, Wfc, bfc, (float*)d_out, G);
    } else {
        float* ws     = (float*)d_ws;
        float* agg1   = ws;
        float* agg2   = agg1 + (size_t)N;
        float* sums   = agg2 + (size_t)8 * N;
        float* counts = sums + (size_t)8 * G;
        float* h1     = counts + (size_t)G;
        hipMemsetAsync(ws, 0, ((size_t)9 * N + (size_t)9 * G) * sizeof(float), stream);
        edge_agg1<<<(E + B - 1) / B, B, 0, stream>>>(ei, x, agg1, E);
        node1F<<<(N + B - 1) / B, B, 0, stream>>>(x, agg1, W1a, b1a, W1b, b1b, h1, N);
        long long tot = (long long)E * H;
        edge_agg2<<<(int)((tot + B - 1) / B), B, 0, stream>>>(ei, h1, agg2, E);
        node2F<<<(N + B - 1) / B, B, 0, stream>>>(h1, agg2, W2a, b2a, W2b, b2b, batch,
                                                  sums, counts, N);
        finalF<<<(G + B - 1) / B, B, 0, stream>>>(sums, counts, Wfc, bfc, (float*)d_out, G);
    }
}